// Round 11
// baseline (143.453 us; speedup 1.0000x reference)
//
#include <hip/hip_runtime.h>

typedef float f32x4 __attribute__((ext_vector_type(4)));
typedef short bf16x8 __attribute__((ext_vector_type(8)));

__device__ __forceinline__ unsigned short f2bf(float f) {
  unsigned int u = __builtin_bit_cast(unsigned int, f);
  u += 0x7fffu + ((u >> 16) & 1u);
  return (unsigned short)(u >> 16);
}
__device__ __forceinline__ float bf2f(unsigned short s) {
  unsigned int u = ((unsigned int)s) << 16;
  return __builtin_bit_cast(float, u);
}

// async global->LDS, 16B per lane. LDS dest = wave-uniform base + lane*16.
__device__ __forceinline__ void gll16(const void* src, void* dst) {
  __builtin_amdgcn_global_load_lds((const __attribute__((address_space(1))) void*)src,
                                   (__attribute__((address_space(3))) void*)dst, 16, 0, 0);
}

// ---------------- prep: ln(x)->XN, ln(y)->ZN  +  144 coalesced 64x64 weight-transpose tiles ----------------
__global__ __launch_bounds__(256) void prep(
    const float* __restrict__ x, const float* __restrict__ y,
    const float* __restrict__ ln1w, const float* __restrict__ ln1b,
    const float* __restrict__ WQ, const float* __restrict__ WK,
    const float* __restrict__ WV, const float* __restrict__ WG,
    const float* __restrict__ WO, const float* __restrict__ F1,
    const float* __restrict__ F2,
    unsigned short* __restrict__ XN, unsigned short* __restrict__ ZN,
    unsigned short* __restrict__ qg, unsigned short* __restrict__ kv,
    unsigned short* __restrict__ wo, unsigned short* __restrict__ f1,
    unsigned short* __restrict__ f2)
{
  __shared__ float tl[64 * 65];
  const int id = blockIdx.x;
  if (id < 8192) {
    const float* X = (id < 4096) ? x : y;
    unsigned short* Y = (id < 4096) ? XN : ZN;
    const int bid = id & 4095;
    const int lane = threadIdx.x & 63;
    const size_t row = (size_t)bid * 4 + (threadIdx.x >> 6);
    const float4 v = *reinterpret_cast<const float4*>(X + row * 256 + lane * 4);
    float s = v.x + v.y + v.z + v.w;
    #pragma unroll
    for (int off = 1; off < 64; off <<= 1) s += __shfl_xor(s, off);
    float mean = s * (1.0f / 256.0f);
    float dx = v.x - mean, dy = v.y - mean, dz = v.z - mean, dw = v.w - mean;
    float q = dx * dx + dy * dy + dz * dz + dw * dw;
    #pragma unroll
    for (int off = 1; off < 64; off <<= 1) q += __shfl_xor(q, off);
    float rstd = rsqrtf(q * (1.0f / 256.0f) + 1e-5f);
    float4 wv = *reinterpret_cast<const float4*>(ln1w + lane * 4);
    float4 bv = *reinterpret_cast<const float4*>(ln1b + lane * 4);
    ushort4 o;
    o.x = f2bf(dx * rstd * wv.x + bv.x);
    o.y = f2bf(dy * rstd * wv.y + bv.y);
    o.z = f2bf(dz * rstd * wv.z + bv.z);
    o.w = f2bf(dw * rstd * wv.w + bv.w);
    *reinterpret_cast<ushort4*>(Y + row * 256 + lane * 4) = o;
    return;
  }
  // ---- weight transpose tiles: src f32 [64 rows x 64 cols] -> dst bf16 [col][row] ----
  const int t = id - 8192;                 // [0,144)
  const float* srcp; unsigned short* dstp; int sstr, dstr;
  if (t < 48) {                            // WQ/WK/WV: [h][d][e] -> [h*64+e][d]
    const float* W = (t < 16) ? WQ : (t < 32) ? WK : WV;
    unsigned short* D = (t < 16) ? qg : kv;
    int tt = t & 15, h = tt >> 2, dt = tt & 3;
    int nof = (t >= 32) ? 256 : 0;
    srcp = W + ((size_t)(h * 256 + dt * 64)) * 64; sstr = 64;
    dstp = D + ((size_t)(nof + h * 64)) * 256 + dt * 64; dstr = 256;
  } else if (t < 64) {                     // WG: [d][n] -> [256+n][d]
    int tt = t - 48, r = tt >> 2, cc = tt & 3;
    srcp = WG + (size_t)(r * 64) * 256 + cc * 64; sstr = 256;
    dstp = qg + (size_t)(256 + cc * 64) * 256 + r * 64; dstr = 256;
  } else if (t < 80) {                     // WO: [d][n] -> [n][d]
    int tt = t - 64, r = tt >> 2, cc = tt & 3;
    srcp = WO + (size_t)(r * 64) * 256 + cc * 64; sstr = 256;
    dstp = wo + (size_t)(cc * 64) * 256 + r * 64; dstr = 256;
  } else if (t < 112) {                    // F1: [d][n] 256x512 -> [n][d]
    int tt = t - 80, r = tt >> 3, cc = tt & 7;
    srcp = F1 + (size_t)(r * 64) * 512 + cc * 64; sstr = 512;
    dstp = f1 + (size_t)(cc * 64) * 256 + r * 64; dstr = 256;
  } else {                                 // F2: [k][n] 512x256 -> [n][k]
    int tt = t - 112, r = tt >> 2, cc = tt & 3;
    srcp = F2 + (size_t)(r * 64) * 256 + cc * 64; sstr = 256;
    dstp = f2 + (size_t)(cc * 64) * 512 + r * 64; dstr = 512;
  }
  {
    const int row = threadIdx.x >> 2, cq = threadIdx.x & 3;
    #pragma unroll
    for (int q = 0; q < 4; ++q) {
      int col = cq * 16 + q * 4;
      float4 v = *reinterpret_cast<const float4*>(srcp + (size_t)row * sstr + col);
      tl[(col + 0) * 65 + row] = v.x;
      tl[(col + 1) * 65 + row] = v.y;
      tl[(col + 2) * 65 + row] = v.z;
      tl[(col + 3) * 65 + row] = v.w;
    }
    __syncthreads();
    const int c2 = threadIdx.x >> 2, kq = threadIdx.x & 3;
    bf16x8 v0, v1;
    #pragma unroll
    for (int k = 0; k < 8; ++k) {
      v0[k] = (short)f2bf(tl[c2 * 65 + kq * 16 + k]);
      v1[k] = (short)f2bf(tl[c2 * 65 + kq * 16 + 8 + k]);
    }
    *reinterpret_cast<bf16x8*>(dstp + (size_t)c2 * dstr + kq * 16) = v0;
    *reinterpret_cast<bf16x8*>(dstp + (size_t)c2 * dstr + kq * 16 + 8) = v1;
  }
}

// ---------------- 128x128 NT GEMM core (BK=64, 4 waves 2x2, each 64x64) ----------------
// MODE 0: qkvg (z=0 -> Q|G, z=1 -> K | V-transposed-via-LDS).  MODE 1: ffn1 (+bias, lrelu -> bf16 stride 512)
template<int MODE>
__global__ __launch_bounds__(256) void gemm128(
    const unsigned short* __restrict__ A0, const unsigned short* __restrict__ A1,
    const unsigned short* __restrict__ B0, const unsigned short* __restrict__ B1,
    unsigned short* __restrict__ o0, unsigned short* __restrict__ o1,
    unsigned short* __restrict__ o2, unsigned short* __restrict__ o3,
    const float* __restrict__ bias)
{
  __shared__ __align__(16) char sA[2][16384];
  __shared__ __align__(16) char sB[2][16384];
  const int tid = threadIdx.x, lane = tid & 63, w = tid >> 6;
  const int z = (MODE == 0) ? blockIdx.z : 0;
  const unsigned short* A = (MODE == 0 && z) ? A1 : A0;
  const unsigned short* Bw = (MODE == 0 && z) ? B1 : B0;
  const int flat = blockIdx.x;
  const int c = flat & 7, jj = flat >> 3;
  const int m0 = (c * 16 + (jj & 15)) * 128;
  const int n0 = (jj >> 4) * 128;
  const int wr = (w >> 1) * 64, wc = (w & 1) * 64;
  const char* Ab = (const char*)A + (size_t)m0 * 512;
  const char* Bb = (const char*)Bw + (size_t)n0 * 512;
  const int srow = lane >> 3;
  const int soff = 16 * ((lane & 7) ^ srow);
  f32x4 acc[4][4] = {};

  auto stage = [&](int bufi, int kt) {
    #pragma unroll
    for (int p = 0; p < 4; ++p) {
      int row = p * 32 + w * 8 + srow;
      gll16(Ab + (size_t)row * 512 + kt + soff, &sA[bufi][p * 4096 + w * 1024]);
      gll16(Bb + (size_t)row * 512 + kt + soff, &sB[bufi][p * 4096 + w * 1024]);
    }
  };

  stage(0, 0);
  asm volatile("s_waitcnt vmcnt(0)" ::: "memory");
  __syncthreads();
  int buf = 0;
  for (int kt = 0; kt < 512; kt += 128) {
    if (kt + 128 < 512) stage(buf ^ 1, kt + 128);
    #pragma unroll
    for (int kk = 0; kk < 2; ++kk) {
      const int ib = kk * 64 + ((lane >> 4) * 16);
      bf16x8 af[4], bfr[4];
      #pragma unroll
      for (int rf = 0; rf < 4; ++rf) {
        int row = wr + rf * 16 + (lane & 15);
        af[rf] = *reinterpret_cast<const bf16x8*>(&sA[buf][row * 128 + (ib ^ ((row & 7) << 4))]);
      }
      #pragma unroll
      for (int cf = 0; cf < 4; ++cf) {
        int row = wc + cf * 16 + (lane & 15);
        bfr[cf] = *reinterpret_cast<const bf16x8*>(&sB[buf][row * 128 + (ib ^ ((row & 7) << 4))]);
      }
      #pragma unroll
      for (int rf = 0; rf < 4; ++rf)
        #pragma unroll
        for (int cf = 0; cf < 4; ++cf)
          acc[rf][cf] = __builtin_amdgcn_mfma_f32_16x16x32_bf16(af[rf], bfr[cf], acc[rf][cf], 0, 0, 0);
    }
    asm volatile("s_waitcnt vmcnt(0)" ::: "memory");
    __syncthreads();
    buf ^= 1;
  }

  if constexpr (MODE == 0) {
    if (z == 1 && n0 >= 256) {
      // ---- V half: LDS-transpose 128x128 -> coalesced 256B-run stores into VT [bh][e][tok] ----
      char* sT = (char*)sA;
      #pragma unroll
      for (int rf = 0; rf < 4; ++rf) {
        #pragma unroll
        for (int cf = 0; cf < 4; ++cf) {
          const int colL = wc + cf * 16 + (lane & 15);
          const int tokL = wr + rf * 16 + ((lane >> 4) * 4);
          f32x4 v = acc[rf][cf];
          #pragma unroll
          for (int j = 0; j < 4; ++j)
            *reinterpret_cast<unsigned short*>(
                sT + colL * 256 + (((tokL + j) * 2) ^ ((colL & 15) << 4))) = f2bf(v[j]);
        }
      }
      __syncthreads();
      const int b10 = m0 & 1023, bb = m0 >> 10;
      #pragma unroll
      for (int it = 0; it < 8; ++it) {
        int idx = it * 256 + tid, colL = idx >> 4, t16 = idx & 15;
        uint4 vv = *reinterpret_cast<uint4*>(sT + colL * 256 + ((t16 * 16) ^ ((colL & 15) << 4)));
        int vc = (n0 - 256) + colL, hh = vc >> 6, e = vc & 63;
        int bh = bb * 4 + hh;
        *reinterpret_cast<uint4*>(o3 + ((((size_t)bh * 64 + e) << 10) + b10 + t16 * 8)) = vv;
      }
      return;
    }
  }

  #pragma unroll
  for (int rf = 0; rf < 4; ++rf) {
    #pragma unroll
    for (int cf = 0; cf < 4; ++cf) {
      const int r0 = m0 + wr + rf * 16 + ((lane >> 4) * 4);
      const int col = n0 + wc + cf * 16 + (lane & 15);
      f32x4 v = acc[rf][cf];
      if constexpr (MODE == 1) {
        float bc = bias[col];
        #pragma unroll
        for (int j = 0; j < 4; ++j) {
          float t = v[j] + bc;
          o0[(size_t)(r0 + j) * 512 + col] = f2bf(t >= 0.0f ? t : 0.01f * t);
        }
      } else {
        if (z == 0) {
          const bool lowhalf = (n0 + wc + cf * 16) < 256;
          unsigned short* dst = lowhalf ? o0 : o1;     // QB | GB
          int ccol = col & 255;
          #pragma unroll
          for (int j = 0; j < 4; ++j) dst[(size_t)(r0 + j) * 256 + ccol] = f2bf(v[j]);
        } else {                                       // K half, token-major
          #pragma unroll
          for (int j = 0; j < 4; ++j) o2[(size_t)(r0 + j) * 256 + col] = f2bf(v[j]);
        }
      }
    }
  }
}

// ---------------- NT GEMM (FFN2): tile 128x64, dbuf prefetch ----------------
template<int EPI>
__global__ __launch_bounds__(256) void gemm_nt(
    const unsigned short* __restrict__ A, const unsigned short* __restrict__ Bw,
    int K, unsigned short* __restrict__ o0,
    const float* __restrict__ bias, const float* __restrict__ resid,
    float* __restrict__ of)
{
  __shared__ __align__(16) char sA[2][16384];
  __shared__ __align__(16) char sB[2][8192];
  const int tid = threadIdx.x, lane = tid & 63, w = tid >> 6;
  const int flat = blockIdx.x + gridDim.x * blockIdx.y;
  const int c = flat & 7, jj = flat >> 3;
  const int m0 = (c * 16 + (jj & 15)) * 128;
  const int n0 = (jj >> 4) * 64;
  const int wr = (w >> 1) * 64, wc = (w & 1) * 32;
  const int K2 = K * 2;
  const char* Ab = (const char*)A + (size_t)m0 * K2;
  const char* Bb = (const char*)Bw + (size_t)n0 * K2;
  const int srow = lane >> 3;
  const int soff = 16 * ((lane & 7) ^ srow);
  f32x4 acc[4][2] = {};

  auto stage = [&](int bufi, int kt) {
    #pragma unroll
    for (int p = 0; p < 4; ++p) {
      int row = p * 32 + w * 8 + srow;
      gll16(Ab + (size_t)row * K2 + kt + soff, &sA[bufi][p * 4096 + w * 1024]);
    }
    #pragma unroll
    for (int p = 0; p < 2; ++p) {
      int row = p * 32 + w * 8 + srow;
      gll16(Bb + (size_t)row * K2 + kt + soff, &sB[bufi][p * 4096 + w * 1024]);
    }
  };

  stage(0, 0);
  asm volatile("s_waitcnt vmcnt(0)" ::: "memory");
  __syncthreads();
  int buf = 0;
  for (int kt = 0; kt < K2; kt += 128) {
    if (kt + 128 < K2) stage(buf ^ 1, kt + 128);
    #pragma unroll
    for (int kk = 0; kk < 2; ++kk) {
      const int ib = kk * 64 + ((lane >> 4) * 16);
      bf16x8 af[4], bfr[2];
      #pragma unroll
      for (int rf = 0; rf < 4; ++rf) {
        int row = wr + rf * 16 + (lane & 15);
        af[rf] = *reinterpret_cast<const bf16x8*>(&sA[buf][row * 128 + (ib ^ ((row & 7) << 4))]);
      }
      #pragma unroll
      for (int cf = 0; cf < 2; ++cf) {
        int row = wc + cf * 16 + (lane & 15);
        bfr[cf] = *reinterpret_cast<const bf16x8*>(&sB[buf][row * 128 + (ib ^ ((row & 7) << 4))]);
      }
      #pragma unroll
      for (int rf = 0; rf < 4; ++rf)
        #pragma unroll
        for (int cf = 0; cf < 2; ++cf)
          acc[rf][cf] = __builtin_amdgcn_mfma_f32_16x16x32_bf16(af[rf], bfr[cf], acc[rf][cf], 0, 0, 0);
    }
    asm volatile("s_waitcnt vmcnt(0)" ::: "memory");
    __syncthreads();
    buf ^= 1;
  }

  #pragma unroll
  for (int rf = 0; rf < 4; ++rf) {
    #pragma unroll
    for (int cf = 0; cf < 2; ++cf) {
      const int r0 = m0 + wr + rf * 16 + ((lane >> 4) * 4);
      const int col = n0 + wc + cf * 16 + (lane & 15);
      f32x4 v = acc[rf][cf];
      if constexpr (EPI == 3) {
        float bc = bias[col];
        #pragma unroll
        for (int j = 0; j < 4; ++j) {
          float t = v[j] + bc;
          o0[(size_t)(r0 + j) * 512 + col] = f2bf(t >= 0.0f ? t : 0.01f * t);
        }
      } else {
        float bc = bias[col];
        #pragma unroll
        for (int j = 0; j < 4; ++j) {
          size_t idx = (size_t)(r0 + j) * 256 + col;
          of[idx] = v[j] + bc + resid[idx];
        }
      }
    }
  }
}

// ---------------- W_O GEMM + residual + fused LayerNorm ----------------
__global__ __launch_bounds__(256) void gemm_wo_ln(
    const unsigned short* __restrict__ AY, const unsigned short* __restrict__ WoT,
    const float* __restrict__ x, const float* __restrict__ ln2w,
    const float* __restrict__ ln2b,
    float* __restrict__ X1, unsigned short* __restrict__ X1N)
{
  __shared__ __align__(16) char sA[2][4096];
  __shared__ __align__(16) char sB[2][32768];
  __shared__ float redS[32][4], redQ[32][4];
  const int tid = threadIdx.x, lane = tid & 63, w = tid >> 6;
  const int id = blockIdx.x;
  const int c = id & 7, j5 = id >> 3;
  const int m0 = (c * 64 + j5) * 32;
  const char* Ab = (const char*)AY + (size_t)m0 * 512;
  const char* Bb = (const char*)WoT;
  const int srow = lane >> 3;
  const int soff = 16 * ((lane & 7) ^ srow);
  f32x4 acc[2][4] = {};

  auto stage = [&](int bufi, int kt) {
    {
      int row = w * 8 + srow;
      gll16(Ab + (size_t)row * 512 + kt + soff, &sA[bufi][w * 1024]);
    }
    #pragma unroll
    for (int p = 0; p < 8; ++p) {
      int row = w * 64 + p * 8 + srow;
      gll16(Bb + (size_t)row * 512 + kt + soff, &sB[bufi][w * 8192 + p * 1024]);
    }
  };

  stage(0, 0);
  asm volatile("s_waitcnt vmcnt(0)" ::: "memory");
  __syncthreads();
  int buf = 0;
  for (int kt = 0; kt < 512; kt += 128) {
    if (kt + 128 < 512) stage(buf ^ 1, kt + 128);
    #pragma unroll
    for (int kk = 0; kk < 2; ++kk) {
      const int ib = kk * 64 + ((lane >> 4) * 16);
      bf16x8 af[2], bfr[4];
      #pragma unroll
      for (int mf = 0; mf < 2; ++mf) {
        int row = mf * 16 + (lane & 15);
        af[mf] = *reinterpret_cast<const bf16x8*>(&sA[buf][row * 128 + (ib ^ ((row & 7) << 4))]);
      }
      #pragma unroll
      for (int nf = 0; nf < 4; ++nf) {
        int row = w * 64 + nf * 16 + (lane & 15);
        bfr[nf] = *reinterpret_cast<const bf16x8*>(&sB[buf][row * 128 + (ib ^ ((row & 7) << 4))]);
      }
      #pragma unroll
      for (int mf = 0; mf < 2; ++mf)
        #pragma unroll
        for (int nf = 0; nf < 4; ++nf)
          acc[mf][nf] = __builtin_amdgcn_mfma_f32_16x16x32_bf16(af[mf], bfr[nf], acc[mf][nf], 0, 0, 0);
    }
    asm volatile("s_waitcnt vmcnt(0)" ::: "memory");
    __syncthreads();
    buf ^= 1;
  }

  #pragma unroll
  for (int mf = 0; mf < 2; ++mf) {
    #pragma unroll
    for (int j = 0; j < 4; ++j) {
      const int rowg = m0 + mf * 16 + ((lane >> 4) * 4) + j;
      float s = 0.0f, q = 0.0f;
      #pragma unroll
      for (int nf = 0; nf < 4; ++nf) {
        const int col = w * 64 + nf * 16 + (lane & 15);
        float v = acc[mf][nf][j] + x[(size_t)rowg * 256 + col];
        acc[mf][nf][j] = v;
        s += v; q += v * v;
      }
      #pragma unroll
      for (int off = 1; off < 16; off <<= 1) { s += __shfl_xor(s, off); q += __shfl_xor(q, off); }
      if ((lane & 15) == 0) {
        int rl = mf * 16 + ((lane >> 4) * 4) + j;
        redS[rl][w] = s; redQ[rl][w] = q;
      }
    }
  }
  __syncthreads();
  #pragma unroll
  for (int mf = 0; mf < 2; ++mf) {
    #pragma unroll
    for (int j = 0; j < 4; ++j) {
      const int rl = mf * 16 + ((lane >> 4) * 4) + j;
      const int rowg = m0 + rl;
      float sm = redS[rl][0] + redS[rl][1] + redS[rl][2] + redS[rl][3];
      float sq = redQ[rl][0] + redQ[rl][1] + redQ[rl][2] + redQ[rl][3];
      float mean = sm * (1.0f / 256.0f);
      float var = sq * (1.0f / 256.0f) - mean * mean;
      float rstd = rsqrtf(var + 1e-5f);
      #pragma unroll
      for (int nf = 0; nf < 4; ++nf) {
        const int col = w * 64 + nf * 16 + (lane & 15);
        float v = acc[mf][nf][j];
        X1[(size_t)rowg * 256 + col] = v;
        X1N[(size_t)rowg * 256 + col] = f2bf((v - mean) * rstd * ln2w[col] + ln2b[col]);
      }
    }
  }
}

// ---------------- retention: per (b,h,q-tile64) causal decay attention ----------------
__global__ __launch_bounds__(256) void attn_ret(
    const unsigned short* __restrict__ Qb, const unsigned short* __restrict__ Kb,
    const unsigned short* __restrict__ Vt, const unsigned short* __restrict__ Gb,
    const float* __restrict__ gnw, const float* __restrict__ gnb,
    unsigned short* __restrict__ AY)
{
  __shared__ __align__(16) char sK[2][8192];
  __shared__ __align__(16) char sV[2][8192];
  __shared__ __align__(16) char sP[8192];
  const int tid = threadIdx.x, lane = tid & 63, w = tid >> 6;
  const int id = blockIdx.x;
  const int c = id & 7, jid = id >> 3;
  const int bh = c * 8 + (jid & 7);
  const int g = jid >> 3;
  const int qt = (g < 4) ? (15 - g) : (g < 8) ? (11 - g) : (g < 12) ? g : (g - 12);
  const int b = bh >> 2, h = bh & 3;

  const float la = logf(1.0f / 32.0f), lb = logf(1.0f / 512.0f);
  const float gamma = 1.0f - expf(la + (lb - la) * ((float)h * (1.0f / 3.0f)));
  const float lg = log2f(gamma);

  const char* Qg = (const char*)Qb
      + ((size_t)(b * 1024 + qt * 64 + w * 16 + (lane & 15))) * 512 + h * 128 + (lane >> 4) * 16;
  const bf16x8 aq0 = *reinterpret_cast<const bf16x8*>(Qg);
  const bf16x8 aq1 = *reinterpret_cast<const bf16x8*>(Qg + 64);

  const int nloc_b = w * 16 + ((lane >> 4) * 4);
  float Aj[4], Bcf[4];
  #pragma unroll
  for (int j = 0; j < 4; ++j) Aj[j] = exp2f((float)(qt * 64 + nloc_b + j) * lg);
  #pragma unroll
  for (int cf = 0; cf < 4; ++cf) Bcf[cf] = exp2f(-(float)(cf * 16 + (lane & 15)) * lg);
  const float g64 = exp2f(-64.0f * lg);

  const char* Kg = (const char*)Kb + ((size_t)(b * 1024)) * 512 + h * 128;
  const char* Vg = (const char*)Vt + ((size_t)bh * 64) * 2048;
  const int srow = lane >> 3;
  const int soff = 16 * ((lane & 7) ^ srow);

  auto stage = [&](int bufi, int t) {
    const char* kb = Kg + (size_t)(t * 64) * 512;
    const char* vb = Vg + (size_t)(t * 64) * 2;
    #pragma unroll
    for (int p = 0; p < 2; ++p) {
      int row = p * 32 + w * 8 + srow;
      gll16(kb + (size_t)row * 512 + soff, &sK[bufi][p * 4096 + w * 1024]);
      gll16(vb + (size_t)row * 2048 + soff, &sV[bufi][p * 4096 + w * 1024]);
    }
  };

  stage(0, 0);
  f32x4 o[4] = {};
  asm volatile("s_waitcnt vmcnt(0)" ::: "memory");
  __syncthreads();
  int buf = 0;

  for (int t = 0; t <= qt; ++t) {
    if (t < qt) stage(buf ^ 1, t + 1);

    f32x4 s4[4] = {};
    #pragma unroll
    for (int kk = 0; kk < 2; ++kk) {
      const int ib = kk * 64 + ((lane >> 4) * 16);
      const bf16x8 aq = kk ? aq1 : aq0;
      #pragma unroll
      for (int cf = 0; cf < 4; ++cf) {
        int kr = cf * 16 + (lane & 15);
        bf16x8 bk = *reinterpret_cast<const bf16x8*>(&sK[buf][kr * 128 + (ib ^ ((kr & 7) << 4))]);
        s4[cf] = __builtin_amdgcn_mfma_f32_16x16x32_bf16(aq, bk, s4[cf], 0, 0, 0);
      }
    }

    const bool diag = (t == qt);
    #pragma unroll
    for (int cf = 0; cf < 4; ++cf) {
      const int mloc = cf * 16 + (lane & 15);
      #pragma unroll
      for (int j = 0; j < 4; ++j) {
        float p = s4[cf][j] * (Aj[j] * Bcf[cf]);
        if (diag && (nloc_b + j - mloc) < 0) p = 0.0f;
        int pr = nloc_b + j;
        *reinterpret_cast<unsigned short*>(sP + pr * 128 + ((mloc * 2) ^ ((pr & 7) << 4))) = f2bf(p);
      }
    }

    #pragma unroll
    for (int kk = 0; kk < 2; ++kk) {
      const int ib = kk * 64 + ((lane >> 4) * 16);
      int pr = w * 16 + (lane & 15);
      bf16x8 ap = *reinterpret_cast<const bf16x8*>(sP + pr * 128 + (ib ^ ((pr & 7) << 4)));
      #pragma unroll
      for (int cf = 0; cf < 4; ++cf) {
        int vr = cf * 16 + (lane & 15);
        bf16x8 bv = *reinterpret_cast<const bf16x8*>(&sV[buf][vr * 128 + (ib ^ ((vr & 7) << 4))]);
        o[cf] = __builtin_amdgcn_mfma_f32_16x16x32_bf16(ap, bv, o[cf], 0, 0, 0);
      }
    }
    #pragma unroll
    for (int j = 0; j < 4; ++j) Aj[j] *= g64;

    asm volatile("s_waitcnt vmcnt(0)" ::: "memory");
    __syncthreads();
    buf ^= 1;
  }

  float gw[4], gb[4];
  #pragma unroll
  for (int cf = 0; cf < 4; ++cf) {
    int col = h * 64 + cf * 16 + (lane & 15);
    gw[cf] = gnw[col]; gb[cf] = gnb[col];
  }
  const int tokb = b * 1024 + qt * 64 + nloc_b;
  #pragma unroll
  for (int j = 0; j < 4; ++j) {
    float sm = 0.0f, sq = 0.0f;
    #pragma unroll
    for (int cf = 0; cf < 4; ++cf) { float xv = o[cf][j]; sm += xv; sq += xv * xv; }
    #pragma unroll
    for (int off = 1; off < 16; off <<= 1) { sm += __shfl_xor(sm, off); sq += __shfl_xor(sq, off); }
    float mean = sm * (1.0f / 64.0f);
    float var = sq * (1.0f / 64.0f) - mean * mean;
    float rstd = rsqrtf(var + 1e-5f);
    size_t tok = (size_t)(tokb + j);
    #pragma unroll
    for (int cf = 0; cf < 4; ++cf) {
      int col = h * 64 + cf * 16 + (lane & 15);
      float yn = (o[cf][j] - mean) * rstd * gw[cf] + gb[cf];
      float gv = bf2f(Gb[tok * 256 + col]);
      float sg = gv / (1.0f + expf(-gv));
      AY[tok * 256 + col] = f2bf(yn * sg);
    }
  }
}

// ---------------- launch ----------------
extern "C" void kernel_launch(void* const* d_in, const int* in_sizes, int n_in,
                              void* d_out, int out_size, void* d_ws, size_t ws_size,
                              hipStream_t stream) {
  const float* x     = (const float*)d_in[0];
  const float* y     = (const float*)d_in[1];
  const float* ln1_w = (const float*)d_in[2];
  const float* ln1_b = (const float*)d_in[3];
  const float* W_Q   = (const float*)d_in[4];
  const float* W_K   = (const float*)d_in[5];
  const float* W_V   = (const float*)d_in[6];
  const float* gn_w  = (const float*)d_in[7];
  const float* gn_b  = (const float*)d_in[8];
  const float* W_G   = (const float*)d_in[9];
  const float* W_O   = (const float*)d_in[10];
  const float* ln2_w = (const float*)d_in[11];
  const float* ln2_b = (const float*)d_in[12];
  const float* ff_w1 = (const float*)d_in[13];
  const float* ff_b1 = (const float*)d_in[14];
  const float* ff_w2 = (const float*)d_in[15];
  const float* ff_b2 = (const float*)d_in[16];

  char* ws = (char*)d_ws;
  const size_t MB = 1048576;
  unsigned short* XN  = (unsigned short*)(ws + 0 * MB);
  unsigned short* ZN  = (unsigned short*)(ws + 8 * MB);
  unsigned short* QB  = (unsigned short*)(ws + 16 * MB);
  unsigned short* KB  = (unsigned short*)(ws + 24 * MB);
  unsigned short* VT  = (unsigned short*)(ws + 32 * MB);
  unsigned short* GB  = (unsigned short*)(ws + 40 * MB);
  unsigned short* WQG = (unsigned short*)(ws + 48 * MB);
  unsigned short* WKV = (unsigned short*)(ws + 48 * MB + 262144);
  unsigned short* WOp = (unsigned short*)(ws + 48 * MB + 524288);
  unsigned short* F1p = (unsigned short*)(ws + 48 * MB + 655360);
  unsigned short* F2p = (unsigned short*)(ws + 48 * MB + 917504);
  float*          X1  = (float*)(ws + 16 * MB);
  unsigned short* X1N = (unsigned short*)(ws + 32 * MB);
  unsigned short* H   = (unsigned short*)(ws + 0 * MB);
  unsigned short* AY  = ZN;
  float* out = (float*)d_out;

  prep<<<8336, 256, 0, stream>>>(x, y, ln1_w, ln1_b, W_Q, W_K, W_V, W_G, W_O,
                                 ff_w1, ff_w2, XN, ZN, WQG, WKV, WOp, F1p, F2p);
  gemm128<0><<<dim3(512, 1, 2), 256, 0, stream>>>(XN, ZN, WQG, WKV, QB, GB, KB, VT, nullptr);
  // MEASUREMENT: attn_ret launched 3x (idempotent). dur delta vs 94.3 = 2*(attn + boundary).
  attn_ret<<<1024, 256, 0, stream>>>(QB, KB, VT, GB, gn_w, gn_b, AY);
  attn_ret<<<1024, 256, 0, stream>>>(QB, KB, VT, GB, gn_w, gn_b, AY);
  attn_ret<<<1024, 256, 0, stream>>>(QB, KB, VT, GB, gn_w, gn_b, AY);
  gemm_wo_ln<<<512, 256, 0, stream>>>(AY, WOp, x, ln2_w, ln2_b, X1, X1N);
  gemm128<1><<<dim3(512, 1, 1), 256, 0, stream>>>(X1N, nullptr, F1p, nullptr, H, nullptr, nullptr, nullptr, ff_b1);
  gemm_nt<4><<<dim3(4, 128), 256, 0, stream>>>(H, F2p, 512, nullptr, ff_b2, X1, out);
}

// Round 12
// 140.514 us; speedup vs baseline: 1.0209x; 1.0209x over previous
//
#include <hip/hip_runtime.h>

typedef float f32x4 __attribute__((ext_vector_type(4)));
typedef short bf16x8 __attribute__((ext_vector_type(8)));

__device__ __forceinline__ unsigned short f2bf(float f) {
  unsigned int u = __builtin_bit_cast(unsigned int, f);
  u += 0x7fffu + ((u >> 16) & 1u);
  return (unsigned short)(u >> 16);
}
__device__ __forceinline__ float bf2f(unsigned short s) {
  unsigned int u = ((unsigned int)s) << 16;
  return __builtin_bit_cast(float, u);
}

// async global->LDS, 16B per lane. LDS dest = wave-uniform base + lane*16.
__device__ __forceinline__ void gll16(const void* src, void* dst) {
  __builtin_amdgcn_global_load_lds((const __attribute__((address_space(1))) void*)src,
                                   (__attribute__((address_space(3))) void*)dst, 16, 0, 0);
}

// ---------------- prep: ln(x)->XN, ln(y)->ZN  +  144 coalesced 64x64 weight-transpose tiles ----------------
__global__ __launch_bounds__(256) void prep(
    const float* __restrict__ x, const float* __restrict__ y,
    const float* __restrict__ ln1w, const float* __restrict__ ln1b,
    const float* __restrict__ WQ, const float* __restrict__ WK,
    const float* __restrict__ WV, const float* __restrict__ WG,
    const float* __restrict__ WO, const float* __restrict__ F1,
    const float* __restrict__ F2,
    unsigned short* __restrict__ XN, unsigned short* __restrict__ ZN,
    unsigned short* __restrict__ qg, unsigned short* __restrict__ kv,
    unsigned short* __restrict__ wo, unsigned short* __restrict__ f1,
    unsigned short* __restrict__ f2)
{
  __shared__ float tl[64 * 65];
  const int id = blockIdx.x;
  if (id < 8192) {
    const float* X = (id < 4096) ? x : y;
    unsigned short* Y = (id < 4096) ? XN : ZN;
    const int bid = id & 4095;
    const int lane = threadIdx.x & 63;
    const size_t row = (size_t)bid * 4 + (threadIdx.x >> 6);
    const float4 v = *reinterpret_cast<const float4*>(X + row * 256 + lane * 4);
    float s = v.x + v.y + v.z + v.w;
    #pragma unroll
    for (int off = 1; off < 64; off <<= 1) s += __shfl_xor(s, off);
    float mean = s * (1.0f / 256.0f);
    float dx = v.x - mean, dy = v.y - mean, dz = v.z - mean, dw = v.w - mean;
    float q = dx * dx + dy * dy + dz * dz + dw * dw;
    #pragma unroll
    for (int off = 1; off < 64; off <<= 1) q += __shfl_xor(q, off);
    float rstd = rsqrtf(q * (1.0f / 256.0f) + 1e-5f);
    float4 wv = *reinterpret_cast<const float4*>(ln1w + lane * 4);
    float4 bv = *reinterpret_cast<const float4*>(ln1b + lane * 4);
    ushort4 o;
    o.x = f2bf(dx * rstd * wv.x + bv.x);
    o.y = f2bf(dy * rstd * wv.y + bv.y);
    o.z = f2bf(dz * rstd * wv.z + bv.z);
    o.w = f2bf(dw * rstd * wv.w + bv.w);
    *reinterpret_cast<ushort4*>(Y + row * 256 + lane * 4) = o;
    return;
  }
  // ---- weight transpose tiles: src f32 [64 rows x 64 cols] -> dst bf16 [col][row] ----
  const int t = id - 8192;                 // [0,144)
  const float* srcp; unsigned short* dstp; int sstr, dstr;
  if (t < 48) {                            // WQ/WK/WV: [h][d][e] -> [h*64+e][d]
    const float* W = (t < 16) ? WQ : (t < 32) ? WK : WV;
    unsigned short* D = (t < 16) ? qg : kv;
    int tt = t & 15, h = tt >> 2, dt = tt & 3;
    int nof = (t >= 32) ? 256 : 0;
    srcp = W + ((size_t)(h * 256 + dt * 64)) * 64; sstr = 64;
    dstp = D + ((size_t)(nof + h * 64)) * 256 + dt * 64; dstr = 256;
  } else if (t < 64) {                     // WG: [d][n] -> [256+n][d]
    int tt = t - 48, r = tt >> 2, cc = tt & 3;
    srcp = WG + (size_t)(r * 64) * 256 + cc * 64; sstr = 256;
    dstp = qg + (size_t)(256 + cc * 64) * 256 + r * 64; dstr = 256;
  } else if (t < 80) {                     // WO: [d][n] -> [n][d]
    int tt = t - 64, r = tt >> 2, cc = tt & 3;
    srcp = WO + (size_t)(r * 64) * 256 + cc * 64; sstr = 256;
    dstp = wo + (size_t)(cc * 64) * 256 + r * 64; dstr = 256;
  } else if (t < 112) {                    // F1: [d][n] 256x512 -> [n][d]
    int tt = t - 80, r = tt >> 3, cc = tt & 7;
    srcp = F1 + (size_t)(r * 64) * 512 + cc * 64; sstr = 512;
    dstp = f1 + (size_t)(cc * 64) * 256 + r * 64; dstr = 256;
  } else {                                 // F2: [k][n] 512x256 -> [n][k]
    int tt = t - 112, r = tt >> 2, cc = tt & 3;
    srcp = F2 + (size_t)(r * 64) * 256 + cc * 64; sstr = 256;
    dstp = f2 + (size_t)(cc * 64) * 512 + r * 64; dstr = 512;
  }
  {
    const int row = threadIdx.x >> 2, cq = threadIdx.x & 3;
    #pragma unroll
    for (int q = 0; q < 4; ++q) {
      int col = cq * 16 + q * 4;
      float4 v = *reinterpret_cast<const float4*>(srcp + (size_t)row * sstr + col);
      tl[(col + 0) * 65 + row] = v.x;
      tl[(col + 1) * 65 + row] = v.y;
      tl[(col + 2) * 65 + row] = v.z;
      tl[(col + 3) * 65 + row] = v.w;
    }
    __syncthreads();
    const int c2 = threadIdx.x >> 2, kq = threadIdx.x & 3;
    bf16x8 v0, v1;
    #pragma unroll
    for (int k = 0; k < 8; ++k) {
      v0[k] = (short)f2bf(tl[c2 * 65 + kq * 16 + k]);
      v1[k] = (short)f2bf(tl[c2 * 65 + kq * 16 + 8 + k]);
    }
    *reinterpret_cast<bf16x8*>(dstp + (size_t)c2 * dstr + kq * 16) = v0;
    *reinterpret_cast<bf16x8*>(dstp + (size_t)c2 * dstr + kq * 16 + 8) = v1;
  }
}

// ---------------- 128x128 NT GEMM core (BK=64, 4 waves 2x2, each 64x64) ----------------
// MODE 0: qkvg (z=0 -> Q|G, z=1 -> K | V-transposed-via-LDS).  MODE 1: ffn1 (+bias, lrelu -> bf16 stride 512)
template<int MODE>
__global__ __launch_bounds__(256) void gemm128(
    const unsigned short* __restrict__ A0, const unsigned short* __restrict__ A1,
    const unsigned short* __restrict__ B0, const unsigned short* __restrict__ B1,
    unsigned short* __restrict__ o0, unsigned short* __restrict__ o1,
    unsigned short* __restrict__ o2, unsigned short* __restrict__ o3,
    const float* __restrict__ bias)
{
  __shared__ __align__(16) char sA[2][16384];
  __shared__ __align__(16) char sB[2][16384];
  const int tid = threadIdx.x, lane = tid & 63, w = tid >> 6;
  const int z = (MODE == 0) ? blockIdx.z : 0;
  const unsigned short* A = (MODE == 0 && z) ? A1 : A0;
  const unsigned short* Bw = (MODE == 0 && z) ? B1 : B0;
  const int flat = blockIdx.x;
  const int c = flat & 7, jj = flat >> 3;
  const int m0 = (c * 16 + (jj & 15)) * 128;
  const int n0 = (jj >> 4) * 128;
  const int wr = (w >> 1) * 64, wc = (w & 1) * 64;
  const char* Ab = (const char*)A + (size_t)m0 * 512;
  const char* Bb = (const char*)Bw + (size_t)n0 * 512;
  const int srow = lane >> 3;
  const int soff = 16 * ((lane & 7) ^ srow);
  f32x4 acc[4][4] = {};

  auto stage = [&](int bufi, int kt) {
    #pragma unroll
    for (int p = 0; p < 4; ++p) {
      int row = p * 32 + w * 8 + srow;
      gll16(Ab + (size_t)row * 512 + kt + soff, &sA[bufi][p * 4096 + w * 1024]);
      gll16(Bb + (size_t)row * 512 + kt + soff, &sB[bufi][p * 4096 + w * 1024]);
    }
  };

  stage(0, 0);
  asm volatile("s_waitcnt vmcnt(0)" ::: "memory");
  __syncthreads();
  int buf = 0;
  for (int kt = 0; kt < 512; kt += 128) {
    if (kt + 128 < 512) stage(buf ^ 1, kt + 128);
    #pragma unroll
    for (int kk = 0; kk < 2; ++kk) {
      const int ib = kk * 64 + ((lane >> 4) * 16);
      bf16x8 af[4], bfr[4];
      #pragma unroll
      for (int rf = 0; rf < 4; ++rf) {
        int row = wr + rf * 16 + (lane & 15);
        af[rf] = *reinterpret_cast<const bf16x8*>(&sA[buf][row * 128 + (ib ^ ((row & 7) << 4))]);
      }
      #pragma unroll
      for (int cf = 0; cf < 4; ++cf) {
        int row = wc + cf * 16 + (lane & 15);
        bfr[cf] = *reinterpret_cast<const bf16x8*>(&sB[buf][row * 128 + (ib ^ ((row & 7) << 4))]);
      }
      #pragma unroll
      for (int rf = 0; rf < 4; ++rf)
        #pragma unroll
        for (int cf = 0; cf < 4; ++cf)
          acc[rf][cf] = __builtin_amdgcn_mfma_f32_16x16x32_bf16(af[rf], bfr[cf], acc[rf][cf], 0, 0, 0);
    }
    asm volatile("s_waitcnt vmcnt(0)" ::: "memory");
    __syncthreads();
    buf ^= 1;
  }

  if constexpr (MODE == 0) {
    if (z == 1 && n0 >= 256) {
      // ---- V half: LDS-transpose 128x128 -> coalesced 256B-run stores into VT [bh][e][tok] ----
      char* sT = (char*)sA;
      #pragma unroll
      for (int rf = 0; rf < 4; ++rf) {
        #pragma unroll
        for (int cf = 0; cf < 4; ++cf) {
          const int colL = wc + cf * 16 + (lane & 15);
          const int tokL = wr + rf * 16 + ((lane >> 4) * 4);
          f32x4 v = acc[rf][cf];
          #pragma unroll
          for (int j = 0; j < 4; ++j)
            *reinterpret_cast<unsigned short*>(
                sT + colL * 256 + (((tokL + j) * 2) ^ ((colL & 15) << 4))) = f2bf(v[j]);
        }
      }
      __syncthreads();
      const int b10 = m0 & 1023, bb = m0 >> 10;
      #pragma unroll
      for (int it = 0; it < 8; ++it) {
        int idx = it * 256 + tid, colL = idx >> 4, t16 = idx & 15;
        uint4 vv = *reinterpret_cast<uint4*>(sT + colL * 256 + ((t16 * 16) ^ ((colL & 15) << 4)));
        int vc = (n0 - 256) + colL, hh = vc >> 6, e = vc & 63;
        int bh = bb * 4 + hh;
        *reinterpret_cast<uint4*>(o3 + ((((size_t)bh * 64 + e) << 10) + b10 + t16 * 8)) = vv;
      }
      return;
    }
  }

  #pragma unroll
  for (int rf = 0; rf < 4; ++rf) {
    #pragma unroll
    for (int cf = 0; cf < 4; ++cf) {
      const int r0 = m0 + wr + rf * 16 + ((lane >> 4) * 4);
      const int col = n0 + wc + cf * 16 + (lane & 15);
      f32x4 v = acc[rf][cf];
      if constexpr (MODE == 1) {
        float bc = bias[col];
        #pragma unroll
        for (int j = 0; j < 4; ++j) {
          float t = v[j] + bc;
          o0[(size_t)(r0 + j) * 512 + col] = f2bf(t >= 0.0f ? t : 0.01f * t);
        }
      } else {
        if (z == 0) {
          const bool lowhalf = (n0 + wc + cf * 16) < 256;
          unsigned short* dst = lowhalf ? o0 : o1;     // QB | GB
          int ccol = col & 255;
          #pragma unroll
          for (int j = 0; j < 4; ++j) dst[(size_t)(r0 + j) * 256 + ccol] = f2bf(v[j]);
        } else {                                       // K half, token-major
          #pragma unroll
          for (int j = 0; j < 4; ++j) o2[(size_t)(r0 + j) * 256 + col] = f2bf(v[j]);
        }
      }
    }
  }
}

// ---------------- NT GEMM (FFN2): tile 128x64, dbuf prefetch ----------------
template<int EPI>
__global__ __launch_bounds__(256) void gemm_nt(
    const unsigned short* __restrict__ A, const unsigned short* __restrict__ Bw,
    int K, unsigned short* __restrict__ o0,
    const float* __restrict__ bias, const float* __restrict__ resid,
    float* __restrict__ of)
{
  __shared__ __align__(16) char sA[2][16384];
  __shared__ __align__(16) char sB[2][8192];
  const int tid = threadIdx.x, lane = tid & 63, w = tid >> 6;
  const int flat = blockIdx.x + gridDim.x * blockIdx.y;
  const int c = flat & 7, jj = flat >> 3;
  const int m0 = (c * 16 + (jj & 15)) * 128;
  const int n0 = (jj >> 4) * 64;
  const int wr = (w >> 1) * 64, wc = (w & 1) * 32;
  const int K2 = K * 2;
  const char* Ab = (const char*)A + (size_t)m0 * K2;
  const char* Bb = (const char*)Bw + (size_t)n0 * K2;
  const int srow = lane >> 3;
  const int soff = 16 * ((lane & 7) ^ srow);
  f32x4 acc[4][2] = {};

  auto stage = [&](int bufi, int kt) {
    #pragma unroll
    for (int p = 0; p < 4; ++p) {
      int row = p * 32 + w * 8 + srow;
      gll16(Ab + (size_t)row * K2 + kt + soff, &sA[bufi][p * 4096 + w * 1024]);
    }
    #pragma unroll
    for (int p = 0; p < 2; ++p) {
      int row = p * 32 + w * 8 + srow;
      gll16(Bb + (size_t)row * K2 + kt + soff, &sB[bufi][p * 4096 + w * 1024]);
    }
  };

  stage(0, 0);
  asm volatile("s_waitcnt vmcnt(0)" ::: "memory");
  __syncthreads();
  int buf = 0;
  for (int kt = 0; kt < K2; kt += 128) {
    if (kt + 128 < K2) stage(buf ^ 1, kt + 128);
    #pragma unroll
    for (int kk = 0; kk < 2; ++kk) {
      const int ib = kk * 64 + ((lane >> 4) * 16);
      bf16x8 af[4], bfr[2];
      #pragma unroll
      for (int rf = 0; rf < 4; ++rf) {
        int row = wr + rf * 16 + (lane & 15);
        af[rf] = *reinterpret_cast<const bf16x8*>(&sA[buf][row * 128 + (ib ^ ((row & 7) << 4))]);
      }
      #pragma unroll
      for (int cf = 0; cf < 2; ++cf) {
        int row = wc + cf * 16 + (lane & 15);
        bfr[cf] = *reinterpret_cast<const bf16x8*>(&sB[buf][row * 128 + (ib ^ ((row & 7) << 4))]);
      }
      #pragma unroll
      for (int rf = 0; rf < 4; ++rf)
        #pragma unroll
        for (int cf = 0; cf < 2; ++cf)
          acc[rf][cf] = __builtin_amdgcn_mfma_f32_16x16x32_bf16(af[rf], bfr[cf], acc[rf][cf], 0, 0, 0);
    }
    asm volatile("s_waitcnt vmcnt(0)" ::: "memory");
    __syncthreads();
    buf ^= 1;
  }

  #pragma unroll
  for (int rf = 0; rf < 4; ++rf) {
    #pragma unroll
    for (int cf = 0; cf < 2; ++cf) {
      const int r0 = m0 + wr + rf * 16 + ((lane >> 4) * 4);
      const int col = n0 + wc + cf * 16 + (lane & 15);
      f32x4 v = acc[rf][cf];
      if constexpr (EPI == 3) {
        float bc = bias[col];
        #pragma unroll
        for (int j = 0; j < 4; ++j) {
          float t = v[j] + bc;
          o0[(size_t)(r0 + j) * 512 + col] = f2bf(t >= 0.0f ? t : 0.01f * t);
        }
      } else {
        float bc = bias[col];
        #pragma unroll
        for (int j = 0; j < 4; ++j) {
          size_t idx = (size_t)(r0 + j) * 256 + col;
          of[idx] = v[j] + bc + resid[idx];
        }
      }
    }
  }
}

// ---------------- W_O GEMM + residual + fused LayerNorm ----------------
__global__ __launch_bounds__(256) void gemm_wo_ln(
    const unsigned short* __restrict__ AY, const unsigned short* __restrict__ WoT,
    const float* __restrict__ x, const float* __restrict__ ln2w,
    const float* __restrict__ ln2b,
    float* __restrict__ X1, unsigned short* __restrict__ X1N)
{
  __shared__ __align__(16) char sA[2][4096];
  __shared__ __align__(16) char sB[2][32768];
  __shared__ float redS[32][4], redQ[32][4];
  const int tid = threadIdx.x, lane = tid & 63, w = tid >> 6;
  const int id = blockIdx.x;
  const int c = id & 7, j5 = id >> 3;
  const int m0 = (c * 64 + j5) * 32;
  const char* Ab = (const char*)AY + (size_t)m0 * 512;
  const char* Bb = (const char*)WoT;
  const int srow = lane >> 3;
  const int soff = 16 * ((lane & 7) ^ srow);
  f32x4 acc[2][4] = {};

  auto stage = [&](int bufi, int kt) {
    {
      int row = w * 8 + srow;
      gll16(Ab + (size_t)row * 512 + kt + soff, &sA[bufi][w * 1024]);
    }
    #pragma unroll
    for (int p = 0; p < 8; ++p) {
      int row = w * 64 + p * 8 + srow;
      gll16(Bb + (size_t)row * 512 + kt + soff, &sB[bufi][w * 8192 + p * 1024]);
    }
  };

  stage(0, 0);
  asm volatile("s_waitcnt vmcnt(0)" ::: "memory");
  __syncthreads();
  int buf = 0;
  for (int kt = 0; kt < 512; kt += 128) {
    if (kt + 128 < 512) stage(buf ^ 1, kt + 128);
    #pragma unroll
    for (int kk = 0; kk < 2; ++kk) {
      const int ib = kk * 64 + ((lane >> 4) * 16);
      bf16x8 af[2], bfr[4];
      #pragma unroll
      for (int mf = 0; mf < 2; ++mf) {
        int row = mf * 16 + (lane & 15);
        af[mf] = *reinterpret_cast<const bf16x8*>(&sA[buf][row * 128 + (ib ^ ((row & 7) << 4))]);
      }
      #pragma unroll
      for (int nf = 0; nf < 4; ++nf) {
        int row = w * 64 + nf * 16 + (lane & 15);
        bfr[nf] = *reinterpret_cast<const bf16x8*>(&sB[buf][row * 128 + (ib ^ ((row & 7) << 4))]);
      }
      #pragma unroll
      for (int mf = 0; mf < 2; ++mf)
        #pragma unroll
        for (int nf = 0; nf < 4; ++nf)
          acc[mf][nf] = __builtin_amdgcn_mfma_f32_16x16x32_bf16(af[mf], bfr[nf], acc[mf][nf], 0, 0, 0);
    }
    asm volatile("s_waitcnt vmcnt(0)" ::: "memory");
    __syncthreads();
    buf ^= 1;
  }

  #pragma unroll
  for (int mf = 0; mf < 2; ++mf) {
    #pragma unroll
    for (int j = 0; j < 4; ++j) {
      const int rowg = m0 + mf * 16 + ((lane >> 4) * 4) + j;
      float s = 0.0f, q = 0.0f;
      #pragma unroll
      for (int nf = 0; nf < 4; ++nf) {
        const int col = w * 64 + nf * 16 + (lane & 15);
        float v = acc[mf][nf][j] + x[(size_t)rowg * 256 + col];
        acc[mf][nf][j] = v;
        s += v; q += v * v;
      }
      #pragma unroll
      for (int off = 1; off < 16; off <<= 1) { s += __shfl_xor(s, off); q += __shfl_xor(q, off); }
      if ((lane & 15) == 0) {
        int rl = mf * 16 + ((lane >> 4) * 4) + j;
        redS[rl][w] = s; redQ[rl][w] = q;
      }
    }
  }
  __syncthreads();
  #pragma unroll
  for (int mf = 0; mf < 2; ++mf) {
    #pragma unroll
    for (int j = 0; j < 4; ++j) {
      const int rl = mf * 16 + ((lane >> 4) * 4) + j;
      const int rowg = m0 + rl;
      float sm = redS[rl][0] + redS[rl][1] + redS[rl][2] + redS[rl][3];
      float sq = redQ[rl][0] + redQ[rl][1] + redQ[rl][2] + redQ[rl][3];
      float mean = sm * (1.0f / 256.0f);
      float var = sq * (1.0f / 256.0f) - mean * mean;
      float rstd = rsqrtf(var + 1e-5f);
      #pragma unroll
      for (int nf = 0; nf < 4; ++nf) {
        const int col = w * 64 + nf * 16 + (lane & 15);
        float v = acc[mf][nf][j];
        X1[(size_t)rowg * 256 + col] = v;
        X1N[(size_t)rowg * 256 + col] = f2bf((v - mean) * rstd * ln2w[col] + ln2b[col]);
      }
    }
  }
}

// ---------------- retention: per (b,h,q-tile64), K/V read DIRECT from L2 (no staging, no barriers) ----------------
// K+V working set per XCD = 2MB < 4MB L2 (XCD-clustered). Each global_load_dwordx4 covers
// 16 rows x 64B fully-consumed lines. sP is wave-private -> zero __syncthreads in kernel.
__global__ __launch_bounds__(256) void attn_ret(
    const unsigned short* __restrict__ Qb, const unsigned short* __restrict__ Kb,
    const unsigned short* __restrict__ Vt, const unsigned short* __restrict__ Gb,
    const float* __restrict__ gnw, const float* __restrict__ gnb,
    unsigned short* __restrict__ AY)
{
  __shared__ __align__(16) char sP[8192];
  const int tid = threadIdx.x, lane = tid & 63, w = tid >> 6;
  const int id = blockIdx.x;
  const int c = id & 7, jid = id >> 3;
  const int bh = c * 8 + (jid & 7);
  const int g = jid >> 3;
  const int qt = (g < 4) ? (15 - g) : (g < 8) ? (11 - g) : (g < 12) ? g : (g - 12);
  const int b = bh >> 2, h = bh & 3;

  const float la = logf(1.0f / 32.0f), lb = logf(1.0f / 512.0f);
  const float gamma = 1.0f - expf(la + (lb - la) * ((float)h * (1.0f / 3.0f)));
  const float lg = log2f(gamma);

  // Q fragments (16B contiguous per lane per kk)
  const char* Qg = (const char*)Qb
      + ((size_t)(b * 1024 + qt * 64 + w * 16 + (lane & 15))) * 512 + h * 128 + (lane >> 4) * 16;
  const bf16x8 aq0 = *reinterpret_cast<const bf16x8*>(Qg);
  const bf16x8 aq1 = *reinterpret_cast<const bf16x8*>(Qg + 64);

  const int nloc_b = w * 16 + ((lane >> 4) * 4);
  float Aj[4], Bcf[4];
  #pragma unroll
  for (int j = 0; j < 4; ++j) Aj[j] = exp2f((float)(qt * 64 + nloc_b + j) * lg);
  #pragma unroll
  for (int cf = 0; cf < 4; ++cf) Bcf[cf] = exp2f(-(float)(cf * 16 + (lane & 15)) * lg);
  const float g64 = exp2f(-64.0f * lg);

  // per-lane fragment bases: B-frag layout = row (lane&15), k-slot (lane>>4)*8 elems (16B)
  const char* Kbase = (const char*)Kb
      + ((size_t)(b * 1024 + (lane & 15))) * 512 + h * 128 + (lane >> 4) * 16;
  const char* Vbase = (const char*)Vt
      + ((size_t)(bh * 64 + (lane & 15))) * 2048 + (lane >> 4) * 16;

  f32x4 o[4] = {};

  for (int t = 0; t <= qt; ++t) {
    // QK^T: K fragments direct from global (L2)
    f32x4 s4[4] = {};
    #pragma unroll
    for (int kk = 0; kk < 2; ++kk) {
      const bf16x8 aq = kk ? aq1 : aq0;
      #pragma unroll
      for (int cf = 0; cf < 4; ++cf) {
        const bf16x8 bk = *reinterpret_cast<const bf16x8*>(
            Kbase + (size_t)(t * 64 + cf * 16) * 512 + kk * 64);
        s4[cf] = __builtin_amdgcn_mfma_f32_16x16x32_bf16(aq, bk, s4[cf], 0, 0, 0);
      }
    }

    // decay + causal mask, write P to wave-private LDS rows (no cross-wave sharing)
    const bool diag = (t == qt);
    #pragma unroll
    for (int cf = 0; cf < 4; ++cf) {
      const int mloc = cf * 16 + (lane & 15);
      #pragma unroll
      for (int j = 0; j < 4; ++j) {
        float p = s4[cf][j] * (Aj[j] * Bcf[cf]);
        if (diag && (nloc_b + j - mloc) < 0) p = 0.0f;
        int pr = nloc_b + j;
        *reinterpret_cast<unsigned short*>(sP + pr * 128 + ((mloc * 2) ^ ((pr & 7) << 4))) = f2bf(p);
      }
    }

    // PV: V fragments direct from global (L2)
    #pragma unroll
    for (int kk = 0; kk < 2; ++kk) {
      const int ib = kk * 64 + ((lane >> 4) * 16);
      int pr = w * 16 + (lane & 15);
      bf16x8 ap = *reinterpret_cast<const bf16x8*>(sP + pr * 128 + (ib ^ ((pr & 7) << 4)));
      #pragma unroll
      for (int cf = 0; cf < 4; ++cf) {
        const bf16x8 bv = *reinterpret_cast<const bf16x8*>(
            Vbase + (size_t)(cf * 16) * 2048 + t * 128 + kk * 64);
        o[cf] = __builtin_amdgcn_mfma_f32_16x16x32_bf16(ap, bv, o[cf], 0, 0, 0);
      }
    }
    #pragma unroll
    for (int j = 0; j < 4; ++j) Aj[j] *= g64;
  }

  // GroupNorm per (token,head) over 64 + gn affine + swish(G) gate -> bf16
  float gw[4], gb[4];
  #pragma unroll
  for (int cf = 0; cf < 4; ++cf) {
    int col = h * 64 + cf * 16 + (lane & 15);
    gw[cf] = gnw[col]; gb[cf] = gnb[col];
  }
  const int tokb = b * 1024 + qt * 64 + nloc_b;
  #pragma unroll
  for (int j = 0; j < 4; ++j) {
    float sm = 0.0f, sq = 0.0f;
    #pragma unroll
    for (int cf = 0; cf < 4; ++cf) { float xv = o[cf][j]; sm += xv; sq += xv * xv; }
    #pragma unroll
    for (int off = 1; off < 16; off <<= 1) { sm += __shfl_xor(sm, off); sq += __shfl_xor(sq, off); }
    float mean = sm * (1.0f / 64.0f);
    float var = sq * (1.0f / 64.0f) - mean * mean;
    float rstd = rsqrtf(var + 1e-5f);
    size_t tok = (size_t)(tokb + j);
    #pragma unroll
    for (int cf = 0; cf < 4; ++cf) {
      int col = h * 64 + cf * 16 + (lane & 15);
      float yn = (o[cf][j] - mean) * rstd * gw[cf] + gb[cf];
      float gv = bf2f(Gb[tok * 256 + col]);
      float sg = gv / (1.0f + expf(-gv));
      AY[tok * 256 + col] = f2bf(yn * sg);
    }
  }
}

// ---------------- launch ----------------
extern "C" void kernel_launch(void* const* d_in, const int* in_sizes, int n_in,
                              void* d_out, int out_size, void* d_ws, size_t ws_size,
                              hipStream_t stream) {
  const float* x     = (const float*)d_in[0];
  const float* y     = (const float*)d_in[1];
  const float* ln1_w = (const float*)d_in[2];
  const float* ln1_b = (const float*)d_in[3];
  const float* W_Q   = (const float*)d_in[4];
  const float* W_K   = (const float*)d_in[5];
  const float* W_V   = (const float*)d_in[6];
  const float* gn_w  = (const float*)d_in[7];
  const float* gn_b  = (const float*)d_in[8];
  const float* W_G   = (const float*)d_in[9];
  const float* W_O   = (const float*)d_in[10];
  const float* ln2_w = (const float*)d_in[11];
  const float* ln2_b = (const float*)d_in[12];
  const float* ff_w1 = (const float*)d_in[13];
  const float* ff_b1 = (const float*)d_in[14];
  const float* ff_w2 = (const float*)d_in[15];
  const float* ff_b2 = (const float*)d_in[16];

  char* ws = (char*)d_ws;
  const size_t MB = 1048576;
  unsigned short* XN  = (unsigned short*)(ws + 0 * MB);
  unsigned short* ZN  = (unsigned short*)(ws + 8 * MB);
  unsigned short* QB  = (unsigned short*)(ws + 16 * MB);
  unsigned short* KB  = (unsigned short*)(ws + 24 * MB);
  unsigned short* VT  = (unsigned short*)(ws + 32 * MB);
  unsigned short* GB  = (unsigned short*)(ws + 40 * MB);
  unsigned short* WQG = (unsigned short*)(ws + 48 * MB);
  unsigned short* WKV = (unsigned short*)(ws + 48 * MB + 262144);
  unsigned short* WOp = (unsigned short*)(ws + 48 * MB + 524288);
  unsigned short* F1p = (unsigned short*)(ws + 48 * MB + 655360);
  unsigned short* F2p = (unsigned short*)(ws + 48 * MB + 917504);
  float*          X1  = (float*)(ws + 16 * MB);
  unsigned short* X1N = (unsigned short*)(ws + 32 * MB);
  unsigned short* H   = (unsigned short*)(ws + 0 * MB);
  unsigned short* AY  = ZN;
  float* out = (float*)d_out;

  prep<<<8336, 256, 0, stream>>>(x, y, ln1_w, ln1_b, W_Q, W_K, W_V, W_G, W_O,
                                 ff_w1, ff_w2, XN, ZN, WQG, WKV, WOp, F1p, F2p);
  gemm128<0><<<dim3(512, 1, 2), 256, 0, stream>>>(XN, ZN, WQG, WKV, QB, GB, KB, VT, nullptr);
  attn_ret<<<1024, 256, 0, stream>>>(QB, KB, VT, GB, gn_w, gn_b, AY);
  gemm_wo_ln<<<512, 256, 0, stream>>>(AY, WOp, x, ln2_w, ln2_b, X1, X1N);
  gemm128<1><<<dim3(512, 1, 1), 256, 0, stream>>>(X1N, nullptr, F1p, nullptr, H, nullptr, nullptr, nullptr, ff_b1);
  gemm_nt<4><<<dim3(4, 128), 256, 0, stream>>>(H, F2p, 512, nullptr, ff_b2, X1, out);
}

// Round 13
// 92.367 us; speedup vs baseline: 1.5531x; 1.5213x over previous
//
#include <hip/hip_runtime.h>

typedef float f32x4 __attribute__((ext_vector_type(4)));
typedef short bf16x8 __attribute__((ext_vector_type(8)));

__device__ __forceinline__ unsigned short f2bf(float f) {
  unsigned int u = __builtin_bit_cast(unsigned int, f);
  u += 0x7fffu + ((u >> 16) & 1u);
  return (unsigned short)(u >> 16);
}
__device__ __forceinline__ float bf2f(unsigned short s) {
  unsigned int u = ((unsigned int)s) << 16;
  return __builtin_bit_cast(float, u);
}

// async global->LDS, 16B per lane. LDS dest = wave-uniform base + lane*16.
__device__ __forceinline__ void gll16(const void* src, void* dst) {
  __builtin_amdgcn_global_load_lds((const __attribute__((address_space(1))) void*)src,
                                   (__attribute__((address_space(3))) void*)dst, 16, 0, 0);
}

// ---------------- prep: ln(x)->XN, ln(y)->ZN  +  144 coalesced 64x64 weight-transpose tiles ----------------
__global__ __launch_bounds__(256) void prep(
    const float* __restrict__ x, const float* __restrict__ y,
    const float* __restrict__ ln1w, const float* __restrict__ ln1b,
    const float* __restrict__ WQ, const float* __restrict__ WK,
    const float* __restrict__ WV, const float* __restrict__ WG,
    const float* __restrict__ WO, const float* __restrict__ F1,
    const float* __restrict__ F2,
    unsigned short* __restrict__ XN, unsigned short* __restrict__ ZN,
    unsigned short* __restrict__ qg, unsigned short* __restrict__ kv,
    unsigned short* __restrict__ wo, unsigned short* __restrict__ f1,
    unsigned short* __restrict__ f2)
{
  __shared__ float tl[64 * 65];
  const int id = blockIdx.x;
  if (id < 8192) {
    const float* X = (id < 4096) ? x : y;
    unsigned short* Y = (id < 4096) ? XN : ZN;
    const int bid = id & 4095;
    const int lane = threadIdx.x & 63;
    const size_t row = (size_t)bid * 4 + (threadIdx.x >> 6);
    const float4 v = *reinterpret_cast<const float4*>(X + row * 256 + lane * 4);
    float s = v.x + v.y + v.z + v.w;
    #pragma unroll
    for (int off = 1; off < 64; off <<= 1) s += __shfl_xor(s, off);
    float mean = s * (1.0f / 256.0f);
    float dx = v.x - mean, dy = v.y - mean, dz = v.z - mean, dw = v.w - mean;
    float q = dx * dx + dy * dy + dz * dz + dw * dw;
    #pragma unroll
    for (int off = 1; off < 64; off <<= 1) q += __shfl_xor(q, off);
    float rstd = rsqrtf(q * (1.0f / 256.0f) + 1e-5f);
    float4 wv = *reinterpret_cast<const float4*>(ln1w + lane * 4);
    float4 bv = *reinterpret_cast<const float4*>(ln1b + lane * 4);
    ushort4 o;
    o.x = f2bf(dx * rstd * wv.x + bv.x);
    o.y = f2bf(dy * rstd * wv.y + bv.y);
    o.z = f2bf(dz * rstd * wv.z + bv.z);
    o.w = f2bf(dw * rstd * wv.w + bv.w);
    *reinterpret_cast<ushort4*>(Y + row * 256 + lane * 4) = o;
    return;
  }
  // ---- weight transpose tiles: src f32 [64 rows x 64 cols] -> dst bf16 [col][row] ----
  const int t = id - 8192;                 // [0,144)
  const float* srcp; unsigned short* dstp; int sstr, dstr;
  if (t < 48) {                            // WQ/WK/WV: [h][d][e] -> [h*64+e][d]
    const float* W = (t < 16) ? WQ : (t < 32) ? WK : WV;
    unsigned short* D = (t < 16) ? qg : kv;
    int tt = t & 15, h = tt >> 2, dt = tt & 3;
    int nof = (t >= 32) ? 256 : 0;
    srcp = W + ((size_t)(h * 256 + dt * 64)) * 64; sstr = 64;
    dstp = D + ((size_t)(nof + h * 64)) * 256 + dt * 64; dstr = 256;
  } else if (t < 64) {                     // WG: [d][n] -> [256+n][d]
    int tt = t - 48, r = tt >> 2, cc = tt & 3;
    srcp = WG + (size_t)(r * 64) * 256 + cc * 64; sstr = 256;
    dstp = qg + (size_t)(256 + cc * 64) * 256 + r * 64; dstr = 256;
  } else if (t < 80) {                     // WO: [d][n] -> [n][d]
    int tt = t - 64, r = tt >> 2, cc = tt & 3;
    srcp = WO + (size_t)(r * 64) * 256 + cc * 64; sstr = 256;
    dstp = wo + (size_t)(cc * 64) * 256 + r * 64; dstr = 256;
  } else if (t < 112) {                    // F1: [d][n] 256x512 -> [n][d]
    int tt = t - 80, r = tt >> 3, cc = tt & 7;
    srcp = F1 + (size_t)(r * 64) * 512 + cc * 64; sstr = 512;
    dstp = f1 + (size_t)(cc * 64) * 256 + r * 64; dstr = 256;
  } else {                                 // F2: [k][n] 512x256 -> [n][k]
    int tt = t - 112, r = tt >> 2, cc = tt & 3;
    srcp = F2 + (size_t)(r * 64) * 256 + cc * 64; sstr = 256;
    dstp = f2 + (size_t)(cc * 64) * 512 + r * 64; dstr = 512;
  }
  {
    const int row = threadIdx.x >> 2, cq = threadIdx.x & 3;
    #pragma unroll
    for (int q = 0; q < 4; ++q) {
      int col = cq * 16 + q * 4;
      float4 v = *reinterpret_cast<const float4*>(srcp + (size_t)row * sstr + col);
      tl[(col + 0) * 65 + row] = v.x;
      tl[(col + 1) * 65 + row] = v.y;
      tl[(col + 2) * 65 + row] = v.z;
      tl[(col + 3) * 65 + row] = v.w;
    }
    __syncthreads();
    const int c2 = threadIdx.x >> 2, kq = threadIdx.x & 3;
    bf16x8 v0, v1;
    #pragma unroll
    for (int k = 0; k < 8; ++k) {
      v0[k] = (short)f2bf(tl[c2 * 65 + kq * 16 + k]);
      v1[k] = (short)f2bf(tl[c2 * 65 + kq * 16 + 8 + k]);
    }
    *reinterpret_cast<bf16x8*>(dstp + (size_t)c2 * dstr + kq * 16) = v0;
    *reinterpret_cast<bf16x8*>(dstp + (size_t)c2 * dstr + kq * 16 + 8) = v1;
  }
}

// ---------------- 128x128 NT GEMM core (BK=64, 4 waves 2x2, each 64x64) ----------------
// MODE 0: qkvg (z=0 -> Q|G, z=1 -> K | V-transposed-via-LDS).  MODE 1: ffn1 (+bias, lrelu -> bf16 stride 512)
template<int MODE>
__global__ __launch_bounds__(256) void gemm128(
    const unsigned short* __restrict__ A0, const unsigned short* __restrict__ A1,
    const unsigned short* __restrict__ B0, const unsigned short* __restrict__ B1,
    unsigned short* __restrict__ o0, unsigned short* __restrict__ o1,
    unsigned short* __restrict__ o2, unsigned short* __restrict__ o3,
    const float* __restrict__ bias)
{
  __shared__ __align__(16) char sA[2][16384];
  __shared__ __align__(16) char sB[2][16384];
  const int tid = threadIdx.x, lane = tid & 63, w = tid >> 6;
  const int z = (MODE == 0) ? blockIdx.z : 0;
  const unsigned short* A = (MODE == 0 && z) ? A1 : A0;
  const unsigned short* Bw = (MODE == 0 && z) ? B1 : B0;
  const int flat = blockIdx.x;
  const int c = flat & 7, jj = flat >> 3;
  const int m0 = (c * 16 + (jj & 15)) * 128;
  const int n0 = (jj >> 4) * 128;
  const int wr = (w >> 1) * 64, wc = (w & 1) * 64;
  const char* Ab = (const char*)A + (size_t)m0 * 512;
  const char* Bb = (const char*)Bw + (size_t)n0 * 512;
  const int srow = lane >> 3;
  const int soff = 16 * ((lane & 7) ^ srow);
  f32x4 acc[4][4] = {};

  auto stage = [&](int bufi, int kt) {
    #pragma unroll
    for (int p = 0; p < 4; ++p) {
      int row = p * 32 + w * 8 + srow;
      gll16(Ab + (size_t)row * 512 + kt + soff, &sA[bufi][p * 4096 + w * 1024]);
      gll16(Bb + (size_t)row * 512 + kt + soff, &sB[bufi][p * 4096 + w * 1024]);
    }
  };

  stage(0, 0);
  asm volatile("s_waitcnt vmcnt(0)" ::: "memory");
  __syncthreads();
  int buf = 0;
  for (int kt = 0; kt < 512; kt += 128) {
    if (kt + 128 < 512) stage(buf ^ 1, kt + 128);
    #pragma unroll
    for (int kk = 0; kk < 2; ++kk) {
      const int ib = kk * 64 + ((lane >> 4) * 16);
      bf16x8 af[4], bfr[4];
      #pragma unroll
      for (int rf = 0; rf < 4; ++rf) {
        int row = wr + rf * 16 + (lane & 15);
        af[rf] = *reinterpret_cast<const bf16x8*>(&sA[buf][row * 128 + (ib ^ ((row & 7) << 4))]);
      }
      #pragma unroll
      for (int cf = 0; cf < 4; ++cf) {
        int row = wc + cf * 16 + (lane & 15);
        bfr[cf] = *reinterpret_cast<const bf16x8*>(&sB[buf][row * 128 + (ib ^ ((row & 7) << 4))]);
      }
      #pragma unroll
      for (int rf = 0; rf < 4; ++rf)
        #pragma unroll
        for (int cf = 0; cf < 4; ++cf)
          acc[rf][cf] = __builtin_amdgcn_mfma_f32_16x16x32_bf16(af[rf], bfr[cf], acc[rf][cf], 0, 0, 0);
    }
    asm volatile("s_waitcnt vmcnt(0)" ::: "memory");
    __syncthreads();
    buf ^= 1;
  }

  if constexpr (MODE == 0) {
    if (z == 1 && n0 >= 256) {
      // ---- V half: LDS-transpose 128x128 -> coalesced 256B-run stores into VT [bh][e][tok] ----
      char* sT = (char*)sA;
      #pragma unroll
      for (int rf = 0; rf < 4; ++rf) {
        #pragma unroll
        for (int cf = 0; cf < 4; ++cf) {
          const int colL = wc + cf * 16 + (lane & 15);
          const int tokL = wr + rf * 16 + ((lane >> 4) * 4);
          f32x4 v = acc[rf][cf];
          #pragma unroll
          for (int j = 0; j < 4; ++j)
            *reinterpret_cast<unsigned short*>(
                sT + colL * 256 + (((tokL + j) * 2) ^ ((colL & 15) << 4))) = f2bf(v[j]);
        }
      }
      __syncthreads();
      const int b10 = m0 & 1023, bb = m0 >> 10;
      #pragma unroll
      for (int it = 0; it < 8; ++it) {
        int idx = it * 256 + tid, colL = idx >> 4, t16 = idx & 15;
        uint4 vv = *reinterpret_cast<uint4*>(sT + colL * 256 + ((t16 * 16) ^ ((colL & 15) << 4)));
        int vc = (n0 - 256) + colL, hh = vc >> 6, e = vc & 63;
        int bh = bb * 4 + hh;
        *reinterpret_cast<uint4*>(o3 + ((((size_t)bh * 64 + e) << 10) + b10 + t16 * 8)) = vv;
      }
      return;
    }
  }

  #pragma unroll
  for (int rf = 0; rf < 4; ++rf) {
    #pragma unroll
    for (int cf = 0; cf < 4; ++cf) {
      const int r0 = m0 + wr + rf * 16 + ((lane >> 4) * 4);
      const int col = n0 + wc + cf * 16 + (lane & 15);
      f32x4 v = acc[rf][cf];
      if constexpr (MODE == 1) {
        float bc = bias[col];
        #pragma unroll
        for (int j = 0; j < 4; ++j) {
          float t = v[j] + bc;
          o0[(size_t)(r0 + j) * 512 + col] = f2bf(t >= 0.0f ? t : 0.01f * t);
        }
      } else {
        if (z == 0) {
          const bool lowhalf = (n0 + wc + cf * 16) < 256;
          unsigned short* dst = lowhalf ? o0 : o1;     // QB | GB
          int ccol = col & 255;
          #pragma unroll
          for (int j = 0; j < 4; ++j) dst[(size_t)(r0 + j) * 256 + ccol] = f2bf(v[j]);
        } else {                                       // K half, token-major
          #pragma unroll
          for (int j = 0; j < 4; ++j) o2[(size_t)(r0 + j) * 256 + col] = f2bf(v[j]);
        }
      }
    }
  }
}

// ---------------- NT GEMM (FFN2): tile 128x64, dbuf prefetch ----------------
template<int EPI>
__global__ __launch_bounds__(256) void gemm_nt(
    const unsigned short* __restrict__ A, const unsigned short* __restrict__ Bw,
    int K, unsigned short* __restrict__ o0,
    const float* __restrict__ bias, const float* __restrict__ resid,
    float* __restrict__ of)
{
  __shared__ __align__(16) char sA[2][16384];
  __shared__ __align__(16) char sB[2][8192];
  const int tid = threadIdx.x, lane = tid & 63, w = tid >> 6;
  const int flat = blockIdx.x + gridDim.x * blockIdx.y;
  const int c = flat & 7, jj = flat >> 3;
  const int m0 = (c * 16 + (jj & 15)) * 128;
  const int n0 = (jj >> 4) * 64;
  const int wr = (w >> 1) * 64, wc = (w & 1) * 32;
  const int K2 = K * 2;
  const char* Ab = (const char*)A + (size_t)m0 * K2;
  const char* Bb = (const char*)Bw + (size_t)n0 * K2;
  const int srow = lane >> 3;
  const int soff = 16 * ((lane & 7) ^ srow);
  f32x4 acc[4][2] = {};

  auto stage = [&](int bufi, int kt) {
    #pragma unroll
    for (int p = 0; p < 4; ++p) {
      int row = p * 32 + w * 8 + srow;
      gll16(Ab + (size_t)row * K2 + kt + soff, &sA[bufi][p * 4096 + w * 1024]);
    }
    #pragma unroll
    for (int p = 0; p < 2; ++p) {
      int row = p * 32 + w * 8 + srow;
      gll16(Bb + (size_t)row * K2 + kt + soff, &sB[bufi][p * 4096 + w * 1024]);
    }
  };

  stage(0, 0);
  asm volatile("s_waitcnt vmcnt(0)" ::: "memory");
  __syncthreads();
  int buf = 0;
  for (int kt = 0; kt < K2; kt += 128) {
    if (kt + 128 < K2) stage(buf ^ 1, kt + 128);
    #pragma unroll
    for (int kk = 0; kk < 2; ++kk) {
      const int ib = kk * 64 + ((lane >> 4) * 16);
      bf16x8 af[4], bfr[2];
      #pragma unroll
      for (int rf = 0; rf < 4; ++rf) {
        int row = wr + rf * 16 + (lane & 15);
        af[rf] = *reinterpret_cast<const bf16x8*>(&sA[buf][row * 128 + (ib ^ ((row & 7) << 4))]);
      }
      #pragma unroll
      for (int cf = 0; cf < 2; ++cf) {
        int row = wc + cf * 16 + (lane & 15);
        bfr[cf] = *reinterpret_cast<const bf16x8*>(&sB[buf][row * 128 + (ib ^ ((row & 7) << 4))]);
      }
      #pragma unroll
      for (int rf = 0; rf < 4; ++rf)
        #pragma unroll
        for (int cf = 0; cf < 2; ++cf)
          acc[rf][cf] = __builtin_amdgcn_mfma_f32_16x16x32_bf16(af[rf], bfr[cf], acc[rf][cf], 0, 0, 0);
    }
    asm volatile("s_waitcnt vmcnt(0)" ::: "memory");
    __syncthreads();
    buf ^= 1;
  }

  #pragma unroll
  for (int rf = 0; rf < 4; ++rf) {
    #pragma unroll
    for (int cf = 0; cf < 2; ++cf) {
      const int r0 = m0 + wr + rf * 16 + ((lane >> 4) * 4);
      const int col = n0 + wc + cf * 16 + (lane & 15);
      f32x4 v = acc[rf][cf];
      if constexpr (EPI == 3) {
        float bc = bias[col];
        #pragma unroll
        for (int j = 0; j < 4; ++j) {
          float t = v[j] + bc;
          o0[(size_t)(r0 + j) * 512 + col] = f2bf(t >= 0.0f ? t : 0.01f * t);
        }
      } else {
        float bc = bias[col];
        #pragma unroll
        for (int j = 0; j < 4; ++j) {
          size_t idx = (size_t)(r0 + j) * 256 + col;
          of[idx] = v[j] + bc + resid[idx];
        }
      }
    }
  }
}

// ---------------- W_O GEMM + residual + fused LayerNorm ----------------
__global__ __launch_bounds__(256) void gemm_wo_ln(
    const unsigned short* __restrict__ AY, const unsigned short* __restrict__ WoT,
    const float* __restrict__ x, const float* __restrict__ ln2w,
    const float* __restrict__ ln2b,
    float* __restrict__ X1, unsigned short* __restrict__ X1N)
{
  __shared__ __align__(16) char sA[2][4096];
  __shared__ __align__(16) char sB[2][32768];
  __shared__ float redS[32][4], redQ[32][4];
  const int tid = threadIdx.x, lane = tid & 63, w = tid >> 6;
  const int id = blockIdx.x;
  const int c = id & 7, j5 = id >> 3;
  const int m0 = (c * 64 + j5) * 32;
  const char* Ab = (const char*)AY + (size_t)m0 * 512;
  const char* Bb = (const char*)WoT;
  const int srow = lane >> 3;
  const int soff = 16 * ((lane & 7) ^ srow);
  f32x4 acc[2][4] = {};

  auto stage = [&](int bufi, int kt) {
    {
      int row = w * 8 + srow;
      gll16(Ab + (size_t)row * 512 + kt + soff, &sA[bufi][w * 1024]);
    }
    #pragma unroll
    for (int p = 0; p < 8; ++p) {
      int row = w * 64 + p * 8 + srow;
      gll16(Bb + (size_t)row * 512 + kt + soff, &sB[bufi][w * 8192 + p * 1024]);
    }
  };

  stage(0, 0);
  asm volatile("s_waitcnt vmcnt(0)" ::: "memory");
  __syncthreads();
  int buf = 0;
  for (int kt = 0; kt < 512; kt += 128) {
    if (kt + 128 < 512) stage(buf ^ 1, kt + 128);
    #pragma unroll
    for (int kk = 0; kk < 2; ++kk) {
      const int ib = kk * 64 + ((lane >> 4) * 16);
      bf16x8 af[2], bfr[4];
      #pragma unroll
      for (int mf = 0; mf < 2; ++mf) {
        int row = mf * 16 + (lane & 15);
        af[mf] = *reinterpret_cast<const bf16x8*>(&sA[buf][row * 128 + (ib ^ ((row & 7) << 4))]);
      }
      #pragma unroll
      for (int nf = 0; nf < 4; ++nf) {
        int row = w * 64 + nf * 16 + (lane & 15);
        bfr[nf] = *reinterpret_cast<const bf16x8*>(&sB[buf][row * 128 + (ib ^ ((row & 7) << 4))]);
      }
      #pragma unroll
      for (int mf = 0; mf < 2; ++mf)
        #pragma unroll
        for (int nf = 0; nf < 4; ++nf)
          acc[mf][nf] = __builtin_amdgcn_mfma_f32_16x16x32_bf16(af[mf], bfr[nf], acc[mf][nf], 0, 0, 0);
    }
    asm volatile("s_waitcnt vmcnt(0)" ::: "memory");
    __syncthreads();
    buf ^= 1;
  }

  #pragma unroll
  for (int mf = 0; mf < 2; ++mf) {
    #pragma unroll
    for (int j = 0; j < 4; ++j) {
      const int rowg = m0 + mf * 16 + ((lane >> 4) * 4) + j;
      float s = 0.0f, q = 0.0f;
      #pragma unroll
      for (int nf = 0; nf < 4; ++nf) {
        const int col = w * 64 + nf * 16 + (lane & 15);
        float v = acc[mf][nf][j] + x[(size_t)rowg * 256 + col];
        acc[mf][nf][j] = v;
        s += v; q += v * v;
      }
      #pragma unroll
      for (int off = 1; off < 16; off <<= 1) { s += __shfl_xor(s, off); q += __shfl_xor(q, off); }
      if ((lane & 15) == 0) {
        int rl = mf * 16 + ((lane >> 4) * 4) + j;
        redS[rl][w] = s; redQ[rl][w] = q;
      }
    }
  }
  __syncthreads();
  #pragma unroll
  for (int mf = 0; mf < 2; ++mf) {
    #pragma unroll
    for (int j = 0; j < 4; ++j) {
      const int rl = mf * 16 + ((lane >> 4) * 4) + j;
      const int rowg = m0 + rl;
      float sm = redS[rl][0] + redS[rl][1] + redS[rl][2] + redS[rl][3];
      float sq = redQ[rl][0] + redQ[rl][1] + redQ[rl][2] + redQ[rl][3];
      float mean = sm * (1.0f / 256.0f);
      float var = sq * (1.0f / 256.0f) - mean * mean;
      float rstd = rsqrtf(var + 1e-5f);
      #pragma unroll
      for (int nf = 0; nf < 4; ++nf) {
        const int col = w * 64 + nf * 16 + (lane & 15);
        float v = acc[mf][nf][j];
        X1[(size_t)rowg * 256 + col] = v;
        X1N[(size_t)rowg * 256 + col] = f2bf((v - mean) * rstd * ln2w[col] + ln2b[col]);
      }
    }
  }
}

// ---------------- retention: swapped QK^T (mfma(K,Q)) -> per-thread fixed q-row n,
// P store = 4x ds_write_b64 (was 16x b16). PV + GN epilogue identical to r7. ----------------
__global__ __launch_bounds__(256) void attn_ret(
    const unsigned short* __restrict__ Qb, const unsigned short* __restrict__ Kb,
    const unsigned short* __restrict__ Vt, const unsigned short* __restrict__ Gb,
    const float* __restrict__ gnw, const float* __restrict__ gnb,
    unsigned short* __restrict__ AY)
{
  __shared__ __align__(16) char sK[2][8192];
  __shared__ __align__(16) char sV[2][8192];
  __shared__ __align__(16) char sP[8192];
  const int tid = threadIdx.x, lane = tid & 63, w = tid >> 6;
  const int id = blockIdx.x;
  const int c = id & 7, jid = id >> 3;
  const int bh = c * 8 + (jid & 7);
  const int g = jid >> 3;
  const int qt = (g < 4) ? (15 - g) : (g < 8) ? (11 - g) : (g < 12) ? g : (g - 12);
  const int b = bh >> 2, h = bh & 3;

  const float la = logf(1.0f / 32.0f), lb = logf(1.0f / 512.0f);
  const float gamma = 1.0f - expf(la + (lb - la) * ((float)h * (1.0f / 3.0f)));
  const float lg = log2f(gamma);

  const char* Qg = (const char*)Qb
      + ((size_t)(b * 1024 + qt * 64 + w * 16 + (lane & 15))) * 512 + h * 128 + (lane >> 4) * 16;
  const bf16x8 aq0 = *reinterpret_cast<const bf16x8*>(Qg);
  const bf16x8 aq1 = *reinterpret_cast<const bf16x8*>(Qg + 64);

  const int nl = w * 16 + (lane & 15);     // this thread's fixed local q-row
  const int hi = lane >> 4;
  float Rt = exp2f((float)(qt * 64 + nl) * lg);      // gamma^(n - 64t), t=0
  const float g64i = exp2f(-64.0f * lg);
  float Mq[4], Mc[4];
  #pragma unroll
  for (int j = 0; j < 4; ++j) Mq[j] = exp2f(-(float)(hi * 4 + j) * lg);
  #pragma unroll
  for (int cf = 0; cf < 4; ++cf) Mc[cf] = exp2f(-(float)(cf * 16) * lg);

  const char* Kg = (const char*)Kb + ((size_t)(b * 1024)) * 512 + h * 128;
  const char* Vg = (const char*)Vt + ((size_t)bh * 64) * 2048;
  const int srow = lane >> 3;
  const int soff = 16 * ((lane & 7) ^ srow);

  auto stage = [&](int bufi, int t) {
    const char* kb = Kg + (size_t)(t * 64) * 512;
    const char* vb = Vg + (size_t)(t * 64) * 2;
    #pragma unroll
    for (int p = 0; p < 2; ++p) {
      int row = p * 32 + w * 8 + srow;
      gll16(kb + (size_t)row * 512 + soff, &sK[bufi][p * 4096 + w * 1024]);
      gll16(vb + (size_t)row * 2048 + soff, &sV[bufi][p * 4096 + w * 1024]);
    }
  };

  stage(0, 0);
  f32x4 o[4] = {};
  asm volatile("s_waitcnt vmcnt(0)" ::: "memory");
  __syncthreads();
  int buf = 0;

  for (int t = 0; t <= qt; ++t) {
    if (t < qt) stage(buf ^ 1, t + 1);

    // swapped QK^T: A = K rows (m), B = Q rows (n). Output: col=lane&15 -> n, row=hi*4+j -> m.
    f32x4 s4[4] = {};
    #pragma unroll
    for (int kk = 0; kk < 2; ++kk) {
      const int ib = kk * 64 + (hi * 16);
      const bf16x8 aq = kk ? aq1 : aq0;
      #pragma unroll
      for (int cf = 0; cf < 4; ++cf) {
        int kr = cf * 16 + (lane & 15);
        bf16x8 bk = *reinterpret_cast<const bf16x8*>(&sK[buf][kr * 128 + (ib ^ ((kr & 7) << 4))]);
        s4[cf] = __builtin_amdgcn_mfma_f32_16x16x32_bf16(bk, aq, s4[cf], 0, 0, 0);
      }
    }

    // decay + causal mask; packed P store: 4 contiguous m per (cf) -> ds_write_b64
    const bool diag = (t == qt);
    #pragma unroll
    for (int cf = 0; cf < 4; ++cf) {
      const float rm = Rt * Mc[cf];
      ushort4 pk;
      {
        float p0 = s4[cf][0] * (rm * Mq[0]);
        float p1 = s4[cf][1] * (rm * Mq[1]);
        float p2 = s4[cf][2] * (rm * Mq[2]);
        float p3 = s4[cf][3] * (rm * Mq[3]);
        if (diag) {
          const int mlb = cf * 16 + hi * 4;
          if (nl - (mlb + 0) < 0) p0 = 0.0f;
          if (nl - (mlb + 1) < 0) p1 = 0.0f;
          if (nl - (mlb + 2) < 0) p2 = 0.0f;
          if (nl - (mlb + 3) < 0) p3 = 0.0f;
        }
        pk.x = f2bf(p0); pk.y = f2bf(p1); pk.z = f2bf(p2); pk.w = f2bf(p3);
      }
      *reinterpret_cast<ushort4*>(
          sP + nl * 128 + ((cf * 32 + hi * 8) ^ ((nl & 7) << 4))) = pk;
    }

    // PV (unchanged): A = P rows (n), B = V^T rows (e). o[cf][j]: n=w*16+hi*4+j, e=cf*16+(lane&15)
    #pragma unroll
    for (int kk = 0; kk < 2; ++kk) {
      const int ib = kk * 64 + (hi * 16);
      int pr = w * 16 + (lane & 15);
      bf16x8 ap = *reinterpret_cast<const bf16x8*>(sP + pr * 128 + (ib ^ ((pr & 7) << 4)));
      #pragma unroll
      for (int cf = 0; cf < 4; ++cf) {
        int vr = cf * 16 + (lane & 15);
        bf16x8 bv = *reinterpret_cast<const bf16x8*>(&sV[buf][vr * 128 + (ib ^ ((vr & 7) << 4))]);
        o[cf] = __builtin_amdgcn_mfma_f32_16x16x32_bf16(ap, bv, o[cf], 0, 0, 0);
      }
    }
    Rt *= g64i;

    asm volatile("s_waitcnt vmcnt(0)" ::: "memory");
    __syncthreads();
    buf ^= 1;
  }

  // GroupNorm per (token,head) over 64 + gn affine + swish(G) gate -> bf16 (r7-identical)
  const int nloc_b = w * 16 + (hi * 4);
  float gw[4], gb[4];
  #pragma unroll
  for (int cf = 0; cf < 4; ++cf) {
    int col = h * 64 + cf * 16 + (lane & 15);
    gw[cf] = gnw[col]; gb[cf] = gnb[col];
  }
  const int tokb = b * 1024 + qt * 64 + nloc_b;
  #pragma unroll
  for (int j = 0; j < 4; ++j) {
    float sm = 0.0f, sq = 0.0f;
    #pragma unroll
    for (int cf = 0; cf < 4; ++cf) { float xv = o[cf][j]; sm += xv; sq += xv * xv; }
    #pragma unroll
    for (int off = 1; off < 16; off <<= 1) { sm += __shfl_xor(sm, off); sq += __shfl_xor(sq, off); }
    float mean = sm * (1.0f / 64.0f);
    float var = sq * (1.0f / 64.0f) - mean * mean;
    float rstd = rsqrtf(var + 1e-5f);
    size_t tok = (size_t)(tokb + j);
    #pragma unroll
    for (int cf = 0; cf < 4; ++cf) {
      int col = h * 64 + cf * 16 + (lane & 15);
      float yn = (o[cf][j] - mean) * rstd * gw[cf] + gb[cf];
      float gv = bf2f(Gb[tok * 256 + col]);
      float sg = gv / (1.0f + expf(-gv));
      AY[tok * 256 + col] = f2bf(yn * sg);
    }
  }
}

// ---------------- launch ----------------
extern "C" void kernel_launch(void* const* d_in, const int* in_sizes, int n_in,
                              void* d_out, int out_size, void* d_ws, size_t ws_size,
                              hipStream_t stream) {
  const float* x     = (const float*)d_in[0];
  const float* y     = (const float*)d_in[1];
  const float* ln1_w = (const float*)d_in[2];
  const float* ln1_b = (const float*)d_in[3];
  const float* W_Q   = (const float*)d_in[4];
  const float* W_K   = (const float*)d_in[5];
  const float* W_V   = (const float*)d_in[6];
  const float* gn_w  = (const float*)d_in[7];
  const float* gn_b  = (const float*)d_in[8];
  const float* W_G   = (const float*)d_in[9];
  const float* W_O   = (const float*)d_in[10];
  const float* ln2_w = (const float*)d_in[11];
  const float* ln2_b = (const float*)d_in[12];
  const float* ff_w1 = (const float*)d_in[13];
  const float* ff_b1 = (const float*)d_in[14];
  const float* ff_w2 = (const float*)d_in[15];
  const float* ff_b2 = (const float*)d_in[16];

  char* ws = (char*)d_ws;
  const size_t MB = 1048576;
  unsigned short* XN  = (unsigned short*)(ws + 0 * MB);
  unsigned short* ZN  = (unsigned short*)(ws + 8 * MB);
  unsigned short* QB  = (unsigned short*)(ws + 16 * MB);
  unsigned short* KB  = (unsigned short*)(ws + 24 * MB);
  unsigned short* VT  = (unsigned short*)(ws + 32 * MB);
  unsigned short* GB  = (unsigned short*)(ws + 40 * MB);
  unsigned short* WQG = (unsigned short*)(ws + 48 * MB);
  unsigned short* WKV = (unsigned short*)(ws + 48 * MB + 262144);
  unsigned short* WOp = (unsigned short*)(ws + 48 * MB + 524288);
  unsigned short* F1p = (unsigned short*)(ws + 48 * MB + 655360);
  unsigned short* F2p = (unsigned short*)(ws + 48 * MB + 917504);
  float*          X1  = (float*)(ws + 16 * MB);
  unsigned short* X1N = (unsigned short*)(ws + 32 * MB);
  unsigned short* H   = (unsigned short*)(ws + 0 * MB);
  unsigned short* AY  = ZN;
  float* out = (float*)d_out;

  prep<<<8336, 256, 0, stream>>>(x, y, ln1_w, ln1_b, W_Q, W_K, W_V, W_G, W_O,
                                 ff_w1, ff_w2, XN, ZN, WQG, WKV, WOp, F1p, F2p);
  gemm128<0><<<dim3(512, 1, 2), 256, 0, stream>>>(XN, ZN, WQG, WKV, QB, GB, KB, VT, nullptr);
  attn_ret<<<1024, 256, 0, stream>>>(QB, KB, VT, GB, gn_w, gn_b, AY);
  gemm_wo_ln<<<512, 256, 0, stream>>>(AY, WOp, x, ln2_w, ln2_b, X1, X1N);
  gemm128<1><<<dim3(512, 1, 1), 256, 0, stream>>>(X1N, nullptr, F1p, nullptr, H, nullptr, nullptr, nullptr, ff_b1);
  gemm_nt<4><<<dim3(4, 128), 256, 0, stream>>>(H, F2p, 512, nullptr, ff_b2, X1, out);
}